// Round 9
// baseline (467.021 us; speedup 1.0000x reference)
//
#include <hip/hip_runtime.h>
#include <math.h>

#define DIM 4096
#define INTER 11008
#define EPS 1e-5f
#define THRESH 0.05f
#define NBLOCKS 1024
#define NGROUPS 64              // 16 blocks per group
#define REG_STRIDE (130 << 10)  // uints per barrier region (flags 4KB apart)

typedef float f4 __attribute__((ext_vector_type(4)));

__device__ __forceinline__ f4 ld4(const float* p) {
    return *reinterpret_cast<const f4*>(p);
}

__device__ __forceinline__ float wave_sum(float v) {
#pragma unroll
    for (int off = 32; off > 0; off >>= 1) v += __shfl_xor(v, off, 64);
    return v;
}

__device__ __forceinline__ float thr(float v) {
    return (fabsf(v) > THRESH) ? v : 0.f;
}

__device__ __forceinline__ float wave_rms_scale(const float* __restrict__ x,
                                                int lane) {
    float ss = 0.f;
#pragma unroll
    for (int k = 0; k < DIM; k += 256) {
        f4 v = ld4(x + k + (lane << 2));
        ss = fmaf(v.x, v.x, ss);
        ss = fmaf(v.y, v.y, ss);
        ss = fmaf(v.z, v.z, ss);
        ss = fmaf(v.w, v.w, ss);
    }
    ss = wave_sum(ss);
    return rsqrtf(ss * (1.f / (float)DIM) + EPS);
}

__device__ __forceinline__ float dot_row_norm(const float* __restrict__ wr,
        const float* __restrict__ x, const float* __restrict__ nw,
        float scale, int lane) {
    float acc[4] = {0.f, 0.f, 0.f, 0.f};
    for (int k = 0; k < DIM; k += 1024) {
#pragma unroll
        for (int u = 0; u < 4; ++u) {
            const int kk = k + (u << 8) + (lane << 2);
            f4 wv = ld4(wr + kk);
            f4 xv = ld4(x + kk);
            f4 nv = ld4(nw + kk);
            float x0 = thr(xv.x * scale * nv.x);
            float x1 = thr(xv.y * scale * nv.y);
            float x2 = thr(xv.z * scale * nv.z);
            float x3 = thr(xv.w * scale * nv.w);
            acc[u] = fmaf(wv.x, x0, acc[u]);
            acc[u] = fmaf(wv.y, x1, acc[u]);
            acc[u] = fmaf(wv.z, x2, acc[u]);
            acc[u] = fmaf(wv.w, x3, acc[u]);
        }
    }
    return wave_sum((acc[0] + acc[1]) + (acc[2] + acc[3]));
}

__device__ __forceinline__ float dot_row(const float* __restrict__ wr,
        const float* __restrict__ x, int lane) {
    float acc[4] = {0.f, 0.f, 0.f, 0.f};
    for (int k = 0; k < DIM; k += 1024) {
#pragma unroll
        for (int u = 0; u < 4; ++u) {
            const int kk = k + (u << 8) + (lane << 2);
            f4 wv = ld4(wr + kk);
            f4 xv = ld4(x + kk);
            acc[u] = fmaf(wv.x, xv.x, acc[u]);
            acc[u] = fmaf(wv.y, xv.y, acc[u]);
            acc[u] = fmaf(wv.z, xv.z, acc[u]);
            acc[u] = fmaf(wv.w, xv.w, acc[u]);
        }
    }
    return wave_sum((acc[0] + acc[1]) + (acc[2] + acc[3]));
}

__device__ __forceinline__ void dot2_row_norm(const float* __restrict__ w1r,
        const float* __restrict__ w3r, const float* __restrict__ h,
        const float* __restrict__ nw, float scale, int lane,
        float& g_out, float& u_out) {
    float g[2] = {0.f, 0.f}, u[2] = {0.f, 0.f};
    for (int k = 0; k < DIM; k += 512) {
#pragma unroll
        for (int p = 0; p < 2; ++p) {
            const int kk = k + (p << 8) + (lane << 2);
            f4 hv = ld4(h + kk);
            f4 nv = ld4(nw + kk);
            f4 av = ld4(w1r + kk);
            f4 bv = ld4(w3r + kk);
            float x0 = thr(hv.x * scale * nv.x);
            float x1 = thr(hv.y * scale * nv.y);
            float x2 = thr(hv.z * scale * nv.z);
            float x3 = thr(hv.w * scale * nv.w);
            g[p] = fmaf(av.x, x0, g[p]);
            g[p] = fmaf(av.y, x1, g[p]);
            g[p] = fmaf(av.z, x2, g[p]);
            g[p] = fmaf(av.w, x3, g[p]);
            u[p] = fmaf(bv.x, x0, u[p]);
            u[p] = fmaf(bv.y, x1, u[p]);
            u[p] = fmaf(bv.z, x2, u[p]);
            u[p] = fmaf(bv.w, x3, u[p]);
        }
    }
    g_out = wave_sum(g[0] + g[1]);
    u_out = wave_sum(u[0] + u[1]);
}

__device__ __forceinline__ float dot_row_inter(const float* __restrict__ wr,
        const float* __restrict__ x, int lane) {
    float acc[4] = {0.f, 0.f, 0.f, 0.f};
    int k = 0;
    for (; k + 1024 <= INTER; k += 1024) {
#pragma unroll
        for (int u = 0; u < 4; ++u) {
            const int kk = k + (u << 8) + (lane << 2);
            f4 wv = ld4(wr + kk);
            f4 xv = ld4(x + kk);
            acc[u] = fmaf(wv.x, xv.x, acc[u]);
            acc[u] = fmaf(wv.y, xv.y, acc[u]);
            acc[u] = fmaf(wv.z, xv.z, acc[u]);
            acc[u] = fmaf(wv.w, xv.w, acc[u]);
        }
    }
#pragma unroll
    for (int u = 0; u < 3; ++u) {  // tail 768 = 3*256
        const int kk = k + (u << 8) + (lane << 2);
        f4 wv = ld4(wr + kk);
        f4 xv = ld4(x + kk);
        acc[u] = fmaf(wv.x, xv.x, acc[u]);
        acc[u] = fmaf(wv.y, xv.y, acc[u]);
        acc[u] = fmaf(wv.z, xv.z, acc[u]);
        acc[u] = fmaf(wv.w, xv.w, acc[u]);
    }
    return wave_sum((acc[0] + acc[1]) + (acc[2] + acc[3]));
}

__device__ __forceinline__ float silu_mul_thr(float g, float u) {
    float s = g / (1.f + expf(-g));
    return thr(s * u);
}

// ---- hierarchical-broadcast global barrier (no single hot line) ----
// Region layout (uints, flags 4KB apart): word w at R + (w<<10):
//   w in [0,64)  : arrive[g]   (16 blocks per group RMW here)
//   w == 64      : root        (64 group-last arrivers RMW here)
//   w in [65,129): rel[g]      (releaser broadcasts; 16 pollers per line)
// Arrival chain of ACQ_REL RMWs gives transitive happens-before; releaser's
// RELEASE stores + pollers' final ACQUIRE load completes it.
// Poll pressure: 16 pollers/line at s_sleep(100)=2.7us -> ~6M/s per line,
// spread over 64 lines — vs r8's 1024 pollers on ONE line (~10^9/s).
__device__ __forceinline__ void global_barrier(unsigned int* R) {
    __syncthreads();
    if (threadIdx.x == 0) {
        const int g = blockIdx.x >> 4;  // 64 groups of 16
        unsigned int* arr  = R + (g << 10);
        unsigned int* root = R + (64 << 10);
        unsigned int* rel  = R + ((65 + g) << 10);
        unsigned int a = __hip_atomic_fetch_add(arr, 1u, __ATOMIC_ACQ_REL,
                                                __HIP_MEMORY_SCOPE_AGENT);
        if (a == 15u) {
            unsigned int r = __hip_atomic_fetch_add(root, 1u, __ATOMIC_ACQ_REL,
                                                    __HIP_MEMORY_SCOPE_AGENT);
            if (r == (unsigned)(NGROUPS - 1)) {
                // releaser: broadcast to all 64 group release lines
                for (int j = 0; j < NGROUPS; ++j)
                    __hip_atomic_store(R + ((65 + j) << 10), 1u,
                                       __ATOMIC_RELEASE,
                                       __HIP_MEMORY_SCOPE_AGENT);
            }
        }
        while (__hip_atomic_load(rel, __ATOMIC_RELAXED,
                                 __HIP_MEMORY_SCOPE_AGENT) == 0u) {
            __builtin_amdgcn_s_sleep(100);  // ~2.7us
        }
        (void)__hip_atomic_load(rel, __ATOMIC_ACQUIRE,
                                __HIP_MEMORY_SCOPE_AGENT);
    }
    __syncthreads();
}

// zero the 129 used words of each of the 3 barrier regions every launch
// (ws poisoned 0xAA; no state may persist across graph replays)
__global__ void init_barriers(unsigned int* bar) {
    for (int i = threadIdx.x; i < 3 * 129; i += 256) {
        const int r = i / 129, w = i % 129;
        bar[(size_t)r * REG_STRIDE + (w << 10)] = 0u;
    }
}

// ---------------- fused kernel, regular launch ----------------
// Identical work partition to rounds 6-8; ONLY barrier internals differ.
__global__ __launch_bounds__(256, 4) void fused_layer_kernel(
        const float* __restrict__ x, const float* __restrict__ wv,
        const float* __restrict__ wo, const float* __restrict__ w1,
        const float* __restrict__ w2, const float* __restrict__ w3,
        const float* __restrict__ anw, const float* __restrict__ fnw,
        float* __restrict__ vt, float* __restrict__ h,
        float* __restrict__ actt, float* __restrict__ out,
        unsigned int* __restrict__ bar) {
    const int lane = threadIdx.x & 63;
    const int wid = (blockIdx.x << 2) + (threadIdx.x >> 6);  // 0..4095

    // Phase 1: vt = thr(wv · thr(rmsnorm(x)*anw))   (SEQ=1: attn out == V)
    {
        const float scale = wave_rms_scale(x, lane);
        float a = dot_row_norm(wv + (size_t)wid * DIM, x, anw, scale, lane);
        if (lane == 0) vt[wid] = thr(a);
    }
    global_barrier(bar);

    // Phase 2: h = x + wo · vt
    {
        float a = dot_row(wo + (size_t)wid * DIM, vt, lane);
        if (lane == 0) h[wid] = x[wid] + a;
    }
    global_barrier(bar + REG_STRIDE);

    // Phase 3: actt[r] = thr(silu(w1·hn)*(w3·hn)), rows wid, wid+4096, wid+8192
    {
        const float scale = wave_rms_scale(h, lane);
        for (int r = wid; r < INTER; r += 4096) {
            float g, u;
            dot2_row_norm(w1 + (size_t)r * DIM, w3 + (size_t)r * DIM,
                          h, fnw, scale, lane, g, u);
            if (lane == 0) actt[r] = silu_mul_thr(g, u);
        }
    }
    global_barrier(bar + 2 * REG_STRIDE);

    // Phase 4: out = h + w2 · actt
    {
        float a = dot_row_inter(w2 + (size_t)wid * INTER, actt, lane);
        if (lane == 0) out[wid] = h[wid] + a;
    }
}

extern "C" void kernel_launch(void* const* d_in, const int* in_sizes, int n_in,
                              void* d_out, int out_size, void* d_ws, size_t ws_size,
                              hipStream_t stream) {
    // setup_inputs order: x, freqs_cis, wqkv, wo, w1, w2, w3, attn_norm_w, ffn_norm_w, mask
    const float* x    = (const float*)d_in[0];
    const float* wqkv = (const float*)d_in[2];
    const float* wo   = (const float*)d_in[3];
    const float* w1   = (const float*)d_in[4];
    const float* w2   = (const float*)d_in[5];
    const float* w3   = (const float*)d_in[6];
    const float* anw  = (const float*)d_in[7];
    const float* fnw  = (const float*)d_in[8];
    float* out = (float*)d_out;

    float* ws   = (float*)d_ws;
    float* vt   = ws;            // 4096
    float* h    = ws + 4096;     // 4096
    float* actt = ws + 8192;     // 11008
    unsigned int* bar = (unsigned int*)(ws + 32768);  // 3 x REG_STRIDE uints

    // V block of wqkv; Q/K rows are dead at SEQ=1 (softmax over 1 key == 1,
    // RoPE at pos 0 is identity).
    const float* wv = wqkv + (size_t)2 * 4096 * DIM;

    init_barriers<<<1, 256, 0, stream>>>(bar);
    fused_layer_kernel<<<NBLOCKS, 256, 0, stream>>>(
        x, wv, wo, w1, w2, w3, anw, fnw, vt, h, actt, out, bar);
}

// Round 10
// 127.440 us; speedup vs baseline: 3.6646x; 3.6646x over previous
//
#include <hip/hip_runtime.h>
#include <math.h>

#define DIM 4096
#define INTER 11008
#define EPS 1e-5f
#define THRESH 0.05f

typedef float f4 __attribute__((ext_vector_type(4)));

__device__ __forceinline__ f4 ld4(const float* p) {
    return *reinterpret_cast<const f4*>(p);
}

__device__ __forceinline__ float wave_sum(float v) {
#pragma unroll
    for (int off = 32; off > 0; off >>= 1) v += __shfl_xor(v, off, 64);
    return v;
}

__device__ __forceinline__ float thr(float v) {
    return (fabsf(v) > THRESH) ? v : 0.f;
}

// Per-wave RMS scale of a DIM-length vector (redundant per wave; the vector
// is L2-resident so this hides under the HBM weight streaming).
__device__ __forceinline__ float wave_rms_scale(const float* __restrict__ x,
                                                int lane) {
    float ss = 0.f;
#pragma unroll
    for (int k = 0; k < DIM; k += 256) {
        f4 v = ld4(x + k + (lane << 2));
        ss = fmaf(v.x, v.x, ss);
        ss = fmaf(v.y, v.y, ss);
        ss = fmaf(v.z, v.z, ss);
        ss = fmaf(v.w, v.w, ss);
    }
    ss = wave_sum(ss);
    return rsqrtf(ss * (1.f / (float)DIM) + EPS);
}

// dot(W[row], thr(x*scale*nw)) over K=DIM
__device__ __forceinline__ float dot_row_norm(const float* __restrict__ wr,
        const float* __restrict__ x, const float* __restrict__ nw,
        float scale, int lane) {
    float acc[4] = {0.f, 0.f, 0.f, 0.f};
    for (int k = 0; k < DIM; k += 1024) {
#pragma unroll
        for (int u = 0; u < 4; ++u) {
            const int kk = k + (u << 8) + (lane << 2);
            f4 wv = ld4(wr + kk);
            f4 xv = ld4(x + kk);
            f4 nv = ld4(nw + kk);
            float x0 = thr(xv.x * scale * nv.x);
            float x1 = thr(xv.y * scale * nv.y);
            float x2 = thr(xv.z * scale * nv.z);
            float x3 = thr(xv.w * scale * nv.w);
            acc[u] = fmaf(wv.x, x0, acc[u]);
            acc[u] = fmaf(wv.y, x1, acc[u]);
            acc[u] = fmaf(wv.z, x2, acc[u]);
            acc[u] = fmaf(wv.w, x3, acc[u]);
        }
    }
    return wave_sum((acc[0] + acc[1]) + (acc[2] + acc[3]));
}

// plain dot(W[row], x) over K=DIM
__device__ __forceinline__ float dot_row(const float* __restrict__ wr,
        const float* __restrict__ x, int lane) {
    float acc[4] = {0.f, 0.f, 0.f, 0.f};
    for (int k = 0; k < DIM; k += 1024) {
#pragma unroll
        for (int u = 0; u < 4; ++u) {
            const int kk = k + (u << 8) + (lane << 2);
            f4 wv = ld4(wr + kk);
            f4 xv = ld4(x + kk);
            acc[u] = fmaf(wv.x, xv.x, acc[u]);
            acc[u] = fmaf(wv.y, xv.y, acc[u]);
            acc[u] = fmaf(wv.z, xv.z, acc[u]);
            acc[u] = fmaf(wv.w, xv.w, acc[u]);
        }
    }
    return wave_sum((acc[0] + acc[1]) + (acc[2] + acc[3]));
}

// simultaneous dots of w1[row],w3[row] against normalized h
__device__ __forceinline__ void dot2_row_norm(const float* __restrict__ w1r,
        const float* __restrict__ w3r, const float* __restrict__ h,
        const float* __restrict__ nw, float scale, int lane,
        float& g_out, float& u_out) {
    float g[2] = {0.f, 0.f}, u[2] = {0.f, 0.f};
    for (int k = 0; k < DIM; k += 512) {
#pragma unroll
        for (int p = 0; p < 2; ++p) {
            const int kk = k + (p << 8) + (lane << 2);
            f4 hv = ld4(h + kk);
            f4 nv = ld4(nw + kk);
            f4 av = ld4(w1r + kk);
            f4 bv = ld4(w3r + kk);
            float x0 = thr(hv.x * scale * nv.x);
            float x1 = thr(hv.y * scale * nv.y);
            float x2 = thr(hv.z * scale * nv.z);
            float x3 = thr(hv.w * scale * nv.w);
            g[p] = fmaf(av.x, x0, g[p]);
            g[p] = fmaf(av.y, x1, g[p]);
            g[p] = fmaf(av.z, x2, g[p]);
            g[p] = fmaf(av.w, x3, g[p]);
            u[p] = fmaf(bv.x, x0, u[p]);
            u[p] = fmaf(bv.y, x1, u[p]);
            u[p] = fmaf(bv.z, x2, u[p]);
            u[p] = fmaf(bv.w, x3, u[p]);
        }
    }
    g_out = wave_sum(g[0] + g[1]);
    u_out = wave_sum(u[0] + u[1]);
}

// dot(W2[row], x) over K=INTER
__device__ __forceinline__ float dot_row_inter(const float* __restrict__ wr,
        const float* __restrict__ x, int lane) {
    float acc[4] = {0.f, 0.f, 0.f, 0.f};
    int k = 0;
    for (; k + 1024 <= INTER; k += 1024) {
#pragma unroll
        for (int u = 0; u < 4; ++u) {
            const int kk = k + (u << 8) + (lane << 2);
            f4 wv = ld4(wr + kk);
            f4 xv = ld4(x + kk);
            acc[u] = fmaf(wv.x, xv.x, acc[u]);
            acc[u] = fmaf(wv.y, xv.y, acc[u]);
            acc[u] = fmaf(wv.z, xv.z, acc[u]);
            acc[u] = fmaf(wv.w, xv.w, acc[u]);
        }
    }
#pragma unroll
    for (int u = 0; u < 3; ++u) {  // tail 768 = 3*256
        const int kk = k + (u << 8) + (lane << 2);
        f4 wv = ld4(wr + kk);
        f4 xv = ld4(x + kk);
        acc[u] = fmaf(wv.x, xv.x, acc[u]);
        acc[u] = fmaf(wv.y, xv.y, acc[u]);
        acc[u] = fmaf(wv.z, xv.z, acc[u]);
        acc[u] = fmaf(wv.w, xv.w, acc[u]);
    }
    return wave_sum((acc[0] + acc[1]) + (acc[2] + acc[3]));
}

__device__ __forceinline__ float silu_mul_thr(float g, float u) {
    float s = g / (1.f + expf(-g));
    return thr(s * u);
}

// ---------------- kernels (round-2 proven chain, 132.9 us) ----------------

__global__ __launch_bounds__(256) void k_v(const float* __restrict__ wv,
        const float* __restrict__ x, const float* __restrict__ anw,
        float* __restrict__ vt) {
    const int lane = threadIdx.x & 63;
    const int wid = (blockIdx.x << 2) + (threadIdx.x >> 6);
    const float scale = wave_rms_scale(x, lane);
    float a = dot_row_norm(wv + (size_t)wid * DIM, x, anw, scale, lane);
    if (lane == 0) vt[wid] = thr(a);
}

__global__ __launch_bounds__(256) void k_o(const float* __restrict__ wo,
        const float* __restrict__ vt, const float* __restrict__ x,
        float* __restrict__ h) {
    const int lane = threadIdx.x & 63;
    const int wid = (blockIdx.x << 2) + (threadIdx.x >> 6);
    float a = dot_row(wo + (size_t)wid * DIM, vt, lane);
    if (lane == 0) h[wid] = x[wid] + a;
}

__global__ __launch_bounds__(256) void k_gu(const float* __restrict__ w1,
        const float* __restrict__ w3, const float* __restrict__ h,
        const float* __restrict__ fnw, float* __restrict__ actt) {
    const int lane = threadIdx.x & 63;
    const int wid = (blockIdx.x << 2) + (threadIdx.x >> 6);
    const float scale = wave_rms_scale(h, lane);
    float g, u;
    dot2_row_norm(w1 + (size_t)wid * DIM, w3 + (size_t)wid * DIM,
                  h, fnw, scale, lane, g, u);
    if (lane == 0) actt[wid] = silu_mul_thr(g, u);
}

__global__ __launch_bounds__(256) void k_d(const float* __restrict__ w2,
        const float* __restrict__ actt, const float* __restrict__ h,
        float* __restrict__ out) {
    const int lane = threadIdx.x & 63;
    const int wid = (blockIdx.x << 2) + (threadIdx.x >> 6);
    float a = dot_row_inter(w2 + (size_t)wid * INTER, actt, lane);
    if (lane == 0) out[wid] = h[wid] + a;
}

extern "C" void kernel_launch(void* const* d_in, const int* in_sizes, int n_in,
                              void* d_out, int out_size, void* d_ws, size_t ws_size,
                              hipStream_t stream) {
    // setup_inputs order: x, freqs_cis, wqkv, wo, w1, w2, w3, attn_norm_w, ffn_norm_w, mask
    const float* x    = (const float*)d_in[0];
    const float* wqkv = (const float*)d_in[2];
    const float* wo   = (const float*)d_in[3];
    const float* w1   = (const float*)d_in[4];
    const float* w2   = (const float*)d_in[5];
    const float* w3   = (const float*)d_in[6];
    const float* anw  = (const float*)d_in[7];
    const float* fnw  = (const float*)d_in[8];
    float* out = (float*)d_out;

    float* ws   = (float*)d_ws;
    float* vt   = ws;            // 4096  : thr(V)  (SEQ=1 -> softmax==1 -> attn out == V)
    float* h    = ws + 4096;     // 4096  : x + wo·vt
    float* actt = ws + 8192;     // 11008 : thr(silu(gate)*up)

    // V block of wqkv; Q/K rows are dead at SEQ=1 (softmax over 1 key == 1,
    // RoPE at pos 0 is identity).
    const float* wv = wqkv + (size_t)2 * 4096 * DIM;

    k_v <<<DIM / 4, 256, 0, stream>>>(wv, x, anw, vt);
    k_o <<<DIM / 4, 256, 0, stream>>>(wo, vt, x, h);
    k_gu<<<INTER / 4, 256, 0, stream>>>(w1, w3, h, fnw, actt);
    k_d <<<DIM / 4, 256, 0, stream>>>(w2, actt, h, out);
}